// Round 9
// baseline (685.676 us; speedup 1.0000x reference)
//
#include <hip/hip_runtime.h>
#include <cstdint>
#include <cstddef>

// ---------------- problem constants ----------------
#define BSZ 64
#define TT  128
#define GG  36
#define CC  256
#define HH  256
#define QQ  16
#define NCLS 10
#define NROW 8192   // TT*BSZ
#define SP_ROWS 16  // rows per k_spatial block (grid 512 -> 2 blocks/CU)

// ---------------- types ----------------
using short8  = __attribute__((ext_vector_type(8))) short;
using f32x4   = __attribute__((ext_vector_type(4))) float;
using half2_t = __attribute__((ext_vector_type(2))) _Float16;
typedef unsigned int u32;
typedef unsigned short u16;

// ---------------- ws layout (bytes) ----------------
#define OFF_WI    0u          // 32768 u32
#define OFF_WF    131072u
#define OFF_WG    262144u
#define OFF_WO    393216u
#define OFF_SAWL  524288u     // 65536 u16 each
#define OFF_TAWL  655360u
#define OFF_TAWV  786432u
#define OFF_SAWC  917504u     // PRE-SWIZZLED: [col][k ^ ((col&7)<<3)]
#define OFF_W32   1048576u    // 5120 f32
#define OFF_WC    1069056u    // 5120 f32
#define OFF_BC    1089536u    // 10 f32 (pad 256)
#define OFF_H0F16 1089792u    // 8192 u32
#define OFF_C0    1122560u    // 16384 f32
#define OFF_HSEQ  1188096u    // 129*64*256 f32
#define OFF_HSEQB 9642240u    // 129*64*256 u16
#define OFF_HPSA  13869312u   // 8192*256 f32
#define OFF_HQ    22257920u
#define OFF_SPAT  30646528u
#define OFF_SPATB 39035136u   // 8192*256 u16
#define OFF_ZSC   43229440u   // 8192 f32
#define WS_NEEDED 43262208u

// ---------------- helpers ----------------
__device__ __forceinline__ float rcp_fast(float x){
#if __has_builtin(__builtin_amdgcn_rcpf)
  return __builtin_amdgcn_rcpf(x);
#else
  return 1.f/x;
#endif
}
__device__ __forceinline__ float fast_sig(float x){ return rcp_fast(1.f+__expf(-x)); }
__device__ __forceinline__ float fast_tanh(float x){ float e=__expf(2.f*x); return 1.f-2.f*rcp_fast(e+1.f); }
__device__ __forceinline__ u16 f2bf(float f){
  u32 u = __builtin_bit_cast(u32, f);
  u += 0x7fffu + ((u>>16)&1u);
  return (u16)(u>>16);
}
__device__ __forceinline__ float bf2f(u16 b){
  u32 u = ((u32)b)<<16; return __builtin_bit_cast(float, u);
}
__device__ __forceinline__ u32 cvtpk_bf16(float a, float b){
  u32 p;
  asm("v_cvt_pk_bf16_f32 %0, %1, %2" : "=v"(p) : "v"(a), "v"(b));
  return p;
}
__device__ __forceinline__ u32 packf16(float a, float b){
  half2_t h; h.x = (_Float16)a; h.y = (_Float16)b;
  return __builtin_bit_cast(u32, h);
}
__device__ __forceinline__ float dot2(u32 w, u32 h, float acc){
#if __has_builtin(__builtin_amdgcn_fdot2)
  return __builtin_amdgcn_fdot2(__builtin_bit_cast(half2_t, w),
                                __builtin_bit_cast(half2_t, h), acc, false);
#else
  half2_t a = __builtin_bit_cast(half2_t, w), b = __builtin_bit_cast(half2_t, h);
  return acc + (float)a.x*(float)b.x + (float)a.y*(float)b.y;
#endif
}
__device__ __forceinline__ f32x4 mfma16(short8 a, short8 b, f32x4 c){
  return __builtin_amdgcn_mfma_f32_16x16x32_bf16(a, b, c, 0, 0, 0);
}

// =====================================================================
// K1: convert whh -> f16 thread layouts; weight mats -> bf16 (sawc in
// XOR-swizzled fragment layout); W32 = W3@W2
// =====================================================================
__global__ void __launch_bounds__(256) k_prep1(const float* __restrict__ whh,
    const float* __restrict__ sawl, const float* __restrict__ tawl,
    const float* __restrict__ tawv, const float* __restrict__ sawc,
    const float* __restrict__ w3, const float* __restrict__ w2, char* ws){
  int blk = blockIdx.x, tid = threadIdx.x;
  if (blk < 512){
    // two whh rows per block -> packed f16 pairs at [c][j]
    u32* wq = (u32*)ws;
    for (int rr = 0; rr < 2; ++rr){
      int row = blk*2 + rr;
      float v  = whh[row*256 + tid];
      float vn = __shfl_down(v, 1);
      if ((tid & 1) == 0){
        int typ = row >> 8;      // 0:i 1:f 2:g 3:o
        int j   = row & 255;
        wq[typ*32768 + (tid>>1)*256 + j] = packf16(v, vn);
      }
    }
  } else if (blk < 544){
    int rel = blk - 512;
    int mat = rel >> 3;
    const float* src; u16* dst;
    if (mat==0){ src=sawl; dst=(u16*)(ws+OFF_SAWL); }
    else if (mat==1){ src=tawl; dst=(u16*)(ws+OFF_TAWL); }
    else if (mat==2){ src=tawv; dst=(u16*)(ws+OFF_TAWV); }
    else { src=sawc; dst=(u16*)(ws+OFF_SAWC); }
    int base = (rel & 7)*8192 + tid;
    if (mat < 3){
      for (int i = 0; i < 32; ++i){ int e = base + i*256; dst[e] = f2bf(src[e]); }
    } else {
      // sawc: swizzled store [col][kk ^ ((col&7)<<3)]
      for (int i = 0; i < 32; ++i){
        int e = base + i*256;
        int col = e >> 8, kk = e & 255;
        dst[col*256 + (kk ^ ((col&7)<<3))] = f2bf(src[e]);
      }
    }
  } else {
    int idx = (blk-544)*256 + tid;   // [0,5120)
    int o = idx >> 9, k2 = idx & 511;
    float acc = 0.f;
    for (int m = 0; m < 512; ++m) acc = fmaf(w3[o*512+m], w2[m*512+k2], acc);
    ((float*)(ws+OFF_W32))[idx] = acc;
  }
}

// =====================================================================
// K2: Wc = W32@W1, bc; and per-batch init h0/c0
// =====================================================================
__global__ void __launch_bounds__(256) k_prep2(const float* __restrict__ w1,
    const float* __restrict__ b1, const float* __restrict__ w3,
    const float* __restrict__ b2, const float* __restrict__ b3,
    const float* __restrict__ gaze,
    const float* __restrict__ ihw1, const float* __restrict__ ihb1,
    const float* __restrict__ ihw2, const float* __restrict__ ihb2,
    const float* __restrict__ icw1, const float* __restrict__ icb1,
    const float* __restrict__ icw2, const float* __restrict__ icb2,
    char* ws){
  int blk = blockIdx.x, tid = threadIdx.x;
  const float* W32 = (const float*)(ws+OFF_W32);
  if (blk < 20){
    int idx = blk*256 + tid; int o = idx>>9, k = idx&511;
    float acc = 0.f;
    for (int m = 0; m < 512; ++m) acc = fmaf(W32[o*512+m], w1[m*512+k], acc);
    ((float*)(ws+OFF_WC))[idx] = acc;
  } else if (blk == 20){
    if (tid < 10){
      float acc = b3[tid];
      for (int m = 0; m < 512; ++m) acc = fmaf(W32[tid*512+m], b1[m], acc);
      for (int m = 0; m < 512; ++m) acc = fmaf(w3[tid*512+m], b2[m], acc);
      ((float*)(ws+OFF_BC))[tid] = acc;
    }
  } else {
    int b = blk - 21;
    __shared__ float red0[128], red1[128], red2[128];
    __shared__ float mg[3];
    __shared__ float x1[256];
    if (tid < 128){
      const float* gp = gaze + b*384 + tid*3;
      red0[tid] = gp[0]; red1[tid] = gp[1]; red2[tid] = gp[2];
    }
    __syncthreads();
    for (int s = 64; s >= 1; s >>= 1){
      if (tid < s){ red0[tid]+=red0[tid+s]; red1[tid]+=red1[tid+s]; red2[tid]+=red2[tid+s]; }
      __syncthreads();
    }
    if (tid == 0){ mg[0]=red0[0]*(1.f/128.f); mg[1]=red1[0]*(1.f/128.f); mg[2]=red2[0]*(1.f/128.f); }
    __syncthreads();
    for (int which = 0; which < 2; ++which){
      const float* aw1 = which? icw1 : ihw1; const float* ab1 = which? icb1 : ihb1;
      const float* aw2 = which? icw2 : ihw2; const float* ab2 = which? icb2 : ihb2;
      float v = fast_tanh(fmaf(aw1[tid*3+2],mg[2], fmaf(aw1[tid*3+1],mg[1], fmaf(aw1[tid*3],mg[0], ab1[tid]))));
      x1[tid] = v;
      __syncthreads();
      float acc = ab2[tid];
      for (int k = 0; k < 256; ++k) acc = fmaf(aw2[tid*256+k], x1[k], acc);
      float h0 = fast_tanh(fast_tanh(acc));
      if (which == 0){
        float* hseq = (float*)(ws+OFF_HSEQ);
        hseq[(size_t)(0*64 + b)*256 + tid] = h0;
        float hn = __shfl_down(h0, 1);
        if ((tid&1)==0){
          ((u32*)(ws+OFF_HSEQB))[((size_t)(0*64+b)*256 + tid)>>1] = ((u32)f2bf(hn)<<16) | f2bf(h0);
          ((u32*)(ws+OFF_H0F16))[b*128 + (tid>>1)] = packf16(h0, hn);
        }
      } else {
        ((float*)(ws+OFF_C0))[b*256 + tid] = h0;
      }
      __syncthreads();
    }
  }
}

// =====================================================================
// K3: LSTM sequential pass — REVERTED to the proven round-5 v2 structure
// (212 us): 512 threads, rowA 128 + rowB-first-64 pairs in regs/AGPRs,
// rowB last 64 pairs in LDS, h double-buffered in LDS, delayed global
// h stores (retire during next dot phase).
// =====================================================================
__global__ void __launch_bounds__(512, 2) k_lstm(const float* __restrict__ gaze,
    const float* __restrict__ wih, const float* __restrict__ bih,
    const float* __restrict__ bhh, char* ws){
  int b = blockIdx.x, tid = threadIdx.x;
  int half = tid >> 8;            // 0: i/g rows, 1: f/o rows
  int j = tid & 255;
  __shared__ u32 lds_w[16*2048];            // 128KB: rowB pairs c=64..127
  __shared__ __align__(16) u32 hbuf[2][128];
  __shared__ float p_lds[256];
  __shared__ float g_lds[384];

  const u32* wq = (const u32*)ws;
  const u32* wA = wq + (half ? 1 : 0) * 32768;   // i or f
  const u32* wB = wq + (half ? 3 : 2) * 32768;   // g or o
  u32 w0[128], w1r[64];
#pragma unroll
  for (int c = 0; c < 128; ++c) w0[c] = wA[c*256 + j];
#pragma unroll
  for (int c = 0; c < 64; ++c)  w1r[c] = wB[c*256 + j];
#pragma unroll
  for (int cq = 0; cq < 16; ++cq)
#pragma unroll
    for (int q = 0; q < 4; ++q)
      lds_w[cq*2048 + tid*4 + q] = wB[(64 + cq*4 + q)*256 + j];

  if (tid < 384) g_lds[tid] = gaze[b*384 + tid];
  if (tid < 128) hbuf[0][tid] = ((const u32*)(ws+OFF_H0F16))[b*128 + tid];
  float creg = half ? ((const float*)(ws+OFF_C0))[b*256 + j] : 0.f;

  int rA = half ? 256 + j : j;
  int rB = half ? 768 + j : 512 + j;
  float baseA = bih[rA] + bhh[rA];
  float baseB = bih[rB] + bhh[rB];
  float uA0 = wih[rA*3], uA1 = wih[rA*3+1], uA2 = wih[rA*3+2];
  float uB0 = wih[rB*3], uB1 = wih[rB*3+1], uB2 = wih[rB*3+2];

  float* hseq = (float*)(ws+OFF_HSEQ);
  u32* hseqb = (u32*)(ws+OFF_HSEQB);
  float hv_prev = 0.f; u32 hpk_prev = 0;
  __syncthreads();

  for (int t = 0; t < 128; ++t){
    int cur = t & 1, nxt = cur ^ 1;
    // delayed global store of h_t (retires during this step's dot phase)
    if (half == 1 && t > 0){
      hseq[((size_t)t*64 + b)*256 + j] = hv_prev;
      if ((j & 1) == 0)
        hseqb[(((size_t)t*64 + b)*256 + j)>>1] = hpk_prev;
    }
    float g0 = g_lds[t*3], g1 = g_lds[t*3+1], g2 = g_lds[t*3+2];
    float aA0 = fmaf(uA2,g2, fmaf(uA1,g1, fmaf(uA0,g0, baseA))), aA1 = 0.f;
    float aB0 = fmaf(uB2,g2, fmaf(uB1,g1, fmaf(uB0,g0, baseB))), aB1 = 0.f;
#pragma unroll
    for (int c4 = 0; c4 < 32; ++c4){
      uint4 h4 = *reinterpret_cast<const uint4*>(&hbuf[cur][c4*4]);
      u32 wb0, wb1, wb2, wb3;
      if (c4 < 16){
        wb0 = w1r[c4*4]; wb1 = w1r[c4*4+1]; wb2 = w1r[c4*4+2]; wb3 = w1r[c4*4+3];
      } else {
        uint4 wv = *reinterpret_cast<const uint4*>(&lds_w[(c4-16)*2048 + tid*4]);
        wb0 = wv.x; wb1 = wv.y; wb2 = wv.z; wb3 = wv.w;
      }
      aA0 = dot2(w0[c4*4+0], h4.x, aA0); aB0 = dot2(wb0, h4.x, aB0);
      aA1 = dot2(w0[c4*4+1], h4.y, aA1); aB1 = dot2(wb1, h4.y, aB1);
      aA0 = dot2(w0[c4*4+2], h4.z, aA0); aB0 = dot2(wb2, h4.z, aB0);
      aA1 = dot2(w0[c4*4+3], h4.w, aA1); aB1 = dot2(wb3, h4.w, aB1);
    }
    float aA = aA0 + aA1, aB = aB0 + aB1;
    if (half == 0){
      p_lds[j] = fast_sig(aA) * fast_tanh(aB);   // sig(i)*tanh(g)
    }
    __syncthreads();
    if (half == 1){
      float p = p_lds[j];
      creg = fmaf(fast_sig(aA), creg, p);        // sig(f)*c + p
      float hv = fast_sig(aB) * fast_tanh(creg); // sig(o)*tanh(c)
      float hn = __shfl_down(hv, 1);
      if ((j & 1) == 0) hbuf[nxt][j>>1] = packf16(hv, hn);
      hv_prev = hv;
      hpk_prev = ((u32)f2bf(hn)<<16) | f2bf(hv);
    }
    __syncthreads();
  }
  // tail: store h_128
  if (half == 1){
    hseq[((size_t)128*64 + b)*256 + j] = hv_prev;
    if ((j & 1) == 0)
      hseqb[(((size_t)128*64 + b)*256 + j)>>1] = hpk_prev;
  }
}

// =====================================================================
// K4: Hp_sa = a@sa_wl^T + (sa_bl+sa_bc);  Hq = a@ta_wl^T + (ta_bl+ta_bv)
// =====================================================================
__global__ void __launch_bounds__(256) k_proj1(const float* __restrict__ sabl,
    const float* __restrict__ sabc, const float* __restrict__ tabl,
    const float* __restrict__ tabv, char* ws){
  int bx = blockIdx.x, which = blockIdx.y;
  const u16* A = (const u16*)(ws+OFF_HSEQB);
  const u16* B = (const u16*)(ws + (which? OFF_TAWL : OFF_SAWL));
  float* Out   = (float*)(ws + (which? OFF_HQ : OFF_HPSA));
  const float* bp1 = which? tabl : sabl;
  const float* bp2 = which? tabv : sabc;
  int tid = threadIdx.x, w = tid>>6, l = tid&63;
  int lr = l&15, lk = l>>4;
  int rb = bx*64;
  short8 afr[4][8];
#pragma unroll
  for (int m = 0; m < 4; ++m)
#pragma unroll
    for (int k = 0; k < 8; ++k)
      afr[m][k] = *(const short8*)(const void*)(A + (size_t)(rb + m*16 + lr)*256 + k*32 + lk*8);
#pragma unroll
  for (int n = 0; n < 4; ++n){
    int cb = w*64 + n*16;
    int col = cb + lr;
    float bias = bp1[col] + bp2[col];
    f32x4 a0 = {0.f,0.f,0.f,0.f}, a1 = a0, a2 = a0, a3 = a0;
#pragma unroll
    for (int k = 0; k < 8; ++k){
      short8 bf = *(const short8*)(const void*)(B + (size_t)col*256 + k*32 + lk*8);
      a0 = mfma16(afr[0][k], bf, a0);
      a1 = mfma16(afr[1][k], bf, a1);
      a2 = mfma16(afr[2][k], bf, a2);
      a3 = mfma16(afr[3][k], bf, a3);
    }
#pragma unroll
    for (int q = 0; q < 4; ++q){
      Out[(size_t)(rb + 0*16 + lk*4 + q)*256 + col] = a0[q] + bias;
      Out[(size_t)(rb + 1*16 + lk*4 + q)*256 + col] = a1[q] + bias;
      Out[(size_t)(rb + 2*16 + lk*4 + q)*256 + col] = a2[q] + bias;
      Out[(size_t)(rb + 3*16 + lk*4 + q)*256 + col] = a3[q] + bias;
    }
  }
}

// =====================================================================
// K5 v5: spatial attention, 512 threads, grid 512 (SP_ROWS=16) so TWO
// blocks fit per CU (LDS ~30KB) -> 4 waves/SIMD latency hiding.
// B (sawc) in registers/AGPRs (MFMA reads AGPR B-operands natively).
// =====================================================================
__global__ void __launch_bounds__(512, 4) k_spatial(const float* __restrict__ feat,
    const float* __restrict__ sawz, char* ws){
  __shared__ __align__(16) u16 featb[48*256];   // rows 36-47 garbage (masked)
  __shared__ __align__(16) float hp[256];
  __shared__ float wzs[256];
  __shared__ float zsbuf[8][48];
  __shared__ float swl[36];
  __shared__ float psum[2][256];
  int bx = blockIdx.x, tid = threadIdx.x, w = tid>>6, l = tid&63;
  int lr = l&15, lk = l>>4;
  int colbase = w*32;
  const float* hpsa = (const float*)(ws+OFF_HPSA);
  const u16* Bw = (const u16*)(ws+OFF_SAWC);

  // B fragments -> registers/AGPRs (once per block)
  short8 breg[2][8];
#pragma unroll
  for (int n = 0; n < 2; ++n){
    int col = colbase + n*16 + lr;
#pragma unroll
    for (int k = 0; k < 8; ++k)
      breg[n][k] = *(const short8*)(const void*)(Bw + (size_t)col*256 + ((k*32 + lk*8) ^ ((col&7)<<3)));
  }
  if (tid < 256) wzs[tid] = sawz[tid];

  // prefetch row 0
  float4 pf[5]; float4 ph;
  {
    int r0 = bx*SP_ROWS;
    int t = r0>>6, b = r0&63;
    const float4* fb = (const float4*)(feat + ((size_t)(b*128 + t))*9216);
#pragma unroll
    for (int ii = 0; ii < 4; ++ii) pf[ii] = fb[tid + ii*512];
    if (tid < 256) pf[4] = fb[2048 + tid];
    if (tid < 64) ph = ((const float4*)(hpsa + (size_t)r0*256))[tid];
  }
  __syncthreads();

  for (int i = 0; i < SP_ROWS; ++i){
    int r = bx*SP_ROWS + i;
    // ---- stage current row's feat (bf16, swizzled) + hp ----
#pragma unroll
    for (int ii = 0; ii < 4; ++ii){
      int e = tid + ii*512;
      int g = e >> 6, c4 = e & 63;
      uint2 pp;
      pp.x = cvtpk_bf16(pf[ii].x, pf[ii].y);
      pp.y = cvtpk_bf16(pf[ii].z, pf[ii].w);
      *reinterpret_cast<uint2*>((u32*)featb + g*128 + ((c4*2) ^ ((g&7)<<2))) = pp;
    }
    if (tid < 256){
      int e = 2048 + tid;
      int g = e >> 6, c4 = e & 63;
      uint2 pp;
      pp.x = cvtpk_bf16(pf[4].x, pf[4].y);
      pp.y = cvtpk_bf16(pf[4].z, pf[4].w);
      *reinterpret_cast<uint2*>((u32*)featb + g*128 + ((c4*2) ^ ((g&7)<<2))) = pp;
    }
    if (tid < 64) *reinterpret_cast<float4*>(hp + tid*4) = ph;
    __syncthreads();
    // ---- prefetch next row ----
    if (i + 1 < SP_ROWS){
      int rn = r + 1;
      int t = rn>>6, b = rn&63;
      const float4* fb = (const float4*)(feat + ((size_t)(b*128 + t))*9216);
#pragma unroll
      for (int ii = 0; ii < 4; ++ii) pf[ii] = fb[tid + ii*512];
      if (tid < 256) pf[4] = fb[2048 + tid];
      if (tid < 64) ph = ((const float4*)(hpsa + (size_t)rn*256))[tid];
    }
    // ---- MFMA: per m load afr, 2 n-groups from registers ----
    float zacc[3][4] = {{0.f}};
#pragma unroll
    for (int m = 0; m < 3; ++m){
      short8 afr[8];
#pragma unroll
      for (int k = 0; k < 8; ++k){
        int g = m*16 + lr;
        afr[k] = *(const short8*)(const void*)(featb + g*256 + ((k*32 + lk*8) ^ ((g&7)<<3)));
      }
#pragma unroll
      for (int n = 0; n < 2; ++n){
        f32x4 a = {0.f,0.f,0.f,0.f};
#pragma unroll
        for (int k = 0; k < 8; ++k) a = mfma16(afr[k], breg[n][k], a);
        int col = colbase + n*16 + lr;
        float hpl = hp[col], wzv = wzs[col];
#pragma unroll
        for (int q = 0; q < 4; ++q)
          zacc[m][q] += fast_tanh(a[q] + hpl)*wzv;
      }
    }
#pragma unroll
    for (int m = 0; m < 3; ++m)
#pragma unroll
      for (int q = 0; q < 4; ++q){
        float v = zacc[m][q];
        v += __shfl_xor(v, 1); v += __shfl_xor(v, 2);
        v += __shfl_xor(v, 4); v += __shfl_xor(v, 8);
        if (lr == 0) zsbuf[w][m*16 + lk*4 + q] = v;
      }
    __syncthreads();
    // ---- softmax over g (wave 0) ----
    if (w == 0){
      float z = -1e30f;
      if (l < 36)
        z = zsbuf[0][l]+zsbuf[1][l]+zsbuf[2][l]+zsbuf[3][l]
          + zsbuf[4][l]+zsbuf[5][l]+zsbuf[6][l]+zsbuf[7][l];
      float mx = z;
      for (int d = 1; d < 64; d <<= 1) mx = fmaxf(mx, __shfl_xor(mx, d));
      float e = (l < 36)? __expf(z - mx) : 0.f;
      float s = e;
      for (int d = 1; d < 64; d <<= 1) s += __shfl_xor(s, d);
      if (l < 36) swl[l] = e * rcp_fast(s);
    }
    __syncthreads();
    // ---- weighted sum: split g 0-17 / 18-35 across thread halves ----
    {
      int hsel = tid >> 8, col = tid & 255;
      float part = 0.f;
#pragma unroll
      for (int gg = 0; gg < 18; ++gg){
        int g = hsel*18 + gg;
        part = fmaf(swl[g], bf2f(featb[g*256 + (col ^ ((g&7)<<3))]), part);
      }
      psum[hsel][col] = part;
    }
    __syncthreads();
    if (tid < 256){
      float acc = psum[0][tid] + psum[1][tid];
      ((float*)(ws+OFF_SPAT))[(size_t)r*256 + tid] = acc;
      float an = __shfl_down(acc, 1);
      if ((tid & 1) == 0)
        ((u32*)(ws+OFF_SPATB))[((size_t)r*256 + tid)>>1] = cvtpk_bf16(acc, an);
    }
  }
}

// =====================================================================
// K6: zscore[r] = rowsum( tanh(spat@ta_wv^T + Hq) * ta_wz )
// =====================================================================
__global__ void __launch_bounds__(256) k_proj2(const float* __restrict__ tawz, char* ws){
  int bx = blockIdx.x;
  int tid = threadIdx.x, w = tid>>6, l = tid&63;
  int lr = l&15, lk = l>>4;
  int rb = bx*64;
  const u16* A = (const u16*)(ws+OFF_SPATB);
  const u16* B = (const u16*)(ws+OFF_TAWV);
  const float* Hq = (const float*)(ws+OFF_HQ);
  __shared__ float zbuf[4][64];
  short8 afr[4][8];
#pragma unroll
  for (int m = 0; m < 4; ++m)
#pragma unroll
    for (int k = 0; k < 8; ++k)
      afr[m][k] = *(const short8*)(const void*)(A + (size_t)(rb + m*16 + lr)*256 + k*32 + lk*8);
  float racc[4][4] = {{0.f}};
#pragma unroll
  for (int n = 0; n < 4; ++n){
    int col = w*64 + n*16 + lr;
    float tzl = tawz[col];
    f32x4 a0 = {0.f,0.f,0.f,0.f}, a1 = a0, a2 = a0, a3 = a0;
#pragma unroll
    for (int k = 0; k < 8; ++k){
      short8 bf = *(const short8*)(const void*)(B + (size_t)col*256 + k*32 + lk*8);
      a0 = mfma16(afr[0][k], bf, a0);
      a1 = mfma16(afr[1][k], bf, a1);
      a2 = mfma16(afr[2][k], bf, a2);
      a3 = mfma16(afr[3][k], bf, a3);
    }
#pragma unroll
    for (int q = 0; q < 4; ++q){
      racc[0][q] += fast_tanh(a0[q] + Hq[(size_t)(rb + 0*16 + lk*4 + q)*256 + col]) * tzl;
      racc[1][q] += fast_tanh(a1[q] + Hq[(size_t)(rb + 1*16 + lk*4 + q)*256 + col]) * tzl;
      racc[2][q] += fast_tanh(a2[q] + Hq[(size_t)(rb + 2*16 + lk*4 + q)*256 + col]) * tzl;
      racc[3][q] += fast_tanh(a3[q] + Hq[(size_t)(rb + 3*16 + lk*4 + q)*256 + col]) * tzl;
    }
  }
#pragma unroll
  for (int m = 0; m < 4; ++m)
#pragma unroll
    for (int q = 0; q < 4; ++q){
      float v = racc[m][q];
      v += __shfl_xor(v, 1); v += __shfl_xor(v, 2);
      v += __shfl_xor(v, 4); v += __shfl_xor(v, 8);
      if (lr == 0) zbuf[w][m*16 + lk*4 + q] = v;
    }
  __syncthreads();
  if (tid < 64)
    ((float*)(ws+OFF_ZSC))[rb + tid] = zbuf[0][tid]+zbuf[1][tid]+zbuf[2][tid]+zbuf[3][tid];
}

// =====================================================================
// K7: windowed temporal softmax + temp + collapsed classifier
// =====================================================================
__global__ void __launch_bounds__(256) k_final(float* __restrict__ out, char* ws){
  int bx = blockIdx.x;
  int b = bx & 63, tb = bx >> 6;
  int t0 = tb*8;
  int tid = threadIdx.x;
  int wv = tid>>6, l = tid&63;
  __shared__ float spw[23][256];
  __shared__ float zw[23];
  __shared__ float WcL[5120];
  __shared__ float bcL[10];
  __shared__ float w16[16];
  __shared__ float wpart[4][10];
  const float* spat = (const float*)(ws+OFF_SPAT);
  const float* zsc  = (const float*)(ws+OFF_ZSC);
  const float* hseq = (const float*)(ws+OFF_HSEQ);
  const float* Wc   = (const float*)(ws+OFF_WC);
#pragma unroll
  for (int i = 0; i < 20; ++i) WcL[tid + i*256] = Wc[tid + i*256];
  if (tid < 10) bcL[tid] = ((const float*)(ws+OFF_BC))[tid];
  for (int i = 0; i < 23; ++i){
    int tau = t0 - 15 + i;
    spw[i][tid] = (tau >= 0)? spat[(size_t)(tau*64 + b)*256 + tid] : 0.f;
  }
  if (tid < 23){
    int tau = t0 - 15 + tid;
    zw[tid] = (tau >= 0)? zsc[tau*64 + b] : -1e9f;
  }
  __syncthreads();
  for (int dt = 0; dt < 8; ++dt){
    int t = t0 + dt;
    if (wv == 0 && l < 16){
      float z = zw[dt + l];
      float mx = z;
      mx = fmaxf(mx, __shfl_xor(mx,1)); mx = fmaxf(mx, __shfl_xor(mx,2));
      mx = fmaxf(mx, __shfl_xor(mx,4)); mx = fmaxf(mx, __shfl_xor(mx,8));
      float e = __expf(z - mx);
      float s = e;
      s += __shfl_xor(s,1); s += __shfl_xor(s,2); s += __shfl_xor(s,4); s += __shfl_xor(s,8);
      w16[l] = e / s;
    }
    __syncthreads();
    float temp = 0.f;
#pragma unroll
    for (int qi = 0; qi < 16; ++qi) temp = fmaf(w16[qi], spw[dt+qi][tid], temp);
    float hc = hseq[(size_t)((t+1)*64 + b)*256 + tid];
    float po[10];
#pragma unroll
    for (int o = 0; o < 10; ++o){
      float v = fmaf(temp, WcL[o*512 + tid], hc*WcL[o*512 + 256 + tid]);
      v += __shfl_xor(v,1);  v += __shfl_xor(v,2);  v += __shfl_xor(v,4);
      v += __shfl_xor(v,8);  v += __shfl_xor(v,16); v += __shfl_xor(v,32);
      po[o] = v;
    }
    if (l == 0){
#pragma unroll
      for (int o = 0; o < 10; ++o) wpart[wv][o] = po[o];
    }
    __syncthreads();
    if (tid < 10)
      out[(size_t)(t*64 + b)*10 + tid] = wpart[0][tid]+wpart[1][tid]+wpart[2][tid]+wpart[3][tid] + bcL[tid];
    __syncthreads();
  }
}

// =====================================================================
extern "C" void kernel_launch(void* const* d_in, const int* in_sizes, int n_in,
                              void* d_out, int out_size, void* d_ws, size_t ws_size,
                              hipStream_t stream){
  const float* feat = (const float*)d_in[0];
  const float* gaze = (const float*)d_in[1];
  const float* ihw1 = (const float*)d_in[2];  const float* ihb1 = (const float*)d_in[3];
  const float* ihw2 = (const float*)d_in[4];  const float* ihb2 = (const float*)d_in[5];
  const float* icw1 = (const float*)d_in[6];  const float* icb1 = (const float*)d_in[7];
  const float* icw2 = (const float*)d_in[8];  const float* icb2 = (const float*)d_in[9];
  const float* wih  = (const float*)d_in[10]; const float* whh  = (const float*)d_in[11];
  const float* bih  = (const float*)d_in[12]; const float* bhh  = (const float*)d_in[13];
  const float* sawl = (const float*)d_in[14]; const float* sabl = (const float*)d_in[15];
  const float* sawc = (const float*)d_in[16]; const float* sabc = (const float*)d_in[17];
  const float* sawz = (const float*)d_in[18];
  const float* tawl = (const float*)d_in[19]; const float* tabl = (const float*)d_in[20];
  const float* tawv = (const float*)d_in[21]; const float* tabv = (const float*)d_in[22];
  const float* tawz = (const float*)d_in[23];
  const float* w1 = (const float*)d_in[24]; const float* b1 = (const float*)d_in[25];
  const float* w2 = (const float*)d_in[26]; const float* b2 = (const float*)d_in[27];
  const float* w3 = (const float*)d_in[28]; const float* b3 = (const float*)d_in[29];
  char* ws = (char*)d_ws;
  float* out = (float*)d_out;
  if (ws_size < (size_t)WS_NEEDED) return;

  k_prep1<<<dim3(564), dim3(256), 0, stream>>>(whh, sawl, tawl, tawv, sawc, w3, w2, ws);
  k_prep2<<<dim3(85), dim3(256), 0, stream>>>(w1, b1, w3, b2, b3, gaze,
      ihw1, ihb1, ihw2, ihb2, icw1, icb1, icw2, icb2, ws);
  k_lstm<<<dim3(64), dim3(512), 0, stream>>>(gaze, wih, bih, bhh, ws);
  k_proj1<<<dim3(128, 2), dim3(256), 0, stream>>>(sabl, sabc, tabl, tabv, ws);
  k_spatial<<<dim3(512), dim3(512), 0, stream>>>(feat, sawz, ws);
  k_proj2<<<dim3(128), dim3(256), 0, stream>>>(tawz, ws);
  k_final<<<dim3(1024), dim3(256), 0, stream>>>(out, ws);
}

// Round 10
// 491.027 us; speedup vs baseline: 1.3964x; 1.3964x over previous
//
#include <hip/hip_runtime.h>
#include <cstdint>
#include <cstddef>

// ---------------- problem constants ----------------
#define BSZ 64
#define TT  128
#define GG  36
#define CC  256
#define HH  256
#define QQ  16
#define NCLS 10
#define NROW 8192   // TT*BSZ
#define SP_ROWS 16  // rows per k_spatial block (grid 512 -> 2 blocks/CU)

// ---------------- types ----------------
using short8  = __attribute__((ext_vector_type(8))) short;
using f32x4   = __attribute__((ext_vector_type(4))) float;
using half2_t = __attribute__((ext_vector_type(2))) _Float16;
typedef unsigned int u32;
typedef unsigned short u16;

// ---------------- ws layout (bytes) ----------------
#define OFF_WI    0u          // 32768 u32
#define OFF_WF    131072u
#define OFF_WG    262144u
#define OFF_WO    393216u
#define OFF_SAWL  524288u     // 65536 u16 each
#define OFF_TAWL  655360u
#define OFF_TAWV  786432u
#define OFF_SAWC  917504u     // PRE-SWIZZLED: [col][k ^ ((col&7)<<3)]
#define OFF_W32   1048576u    // 5120 f32
#define OFF_WC    1069056u    // 5120 f32
#define OFF_BC    1089536u    // 10 f32 (pad 256)
#define OFF_H0F16 1089792u    // 8192 u32
#define OFF_C0    1122560u    // 16384 f32
#define OFF_HSEQ  1188096u    // 129*64*256 f32
#define OFF_HSEQB 9642240u    // 129*64*256 u16
#define OFF_HPSA  13869312u   // 8192*256 f32
#define OFF_HQ    22257920u
#define OFF_SPAT  30646528u
#define OFF_SPATB 39035136u   // 8192*256 u16
#define OFF_ZSC   43229440u   // 8192 f32
#define WS_NEEDED 43262208u

// ---------------- helpers ----------------
__device__ __forceinline__ float rcp_fast(float x){
#if __has_builtin(__builtin_amdgcn_rcpf)
  return __builtin_amdgcn_rcpf(x);
#else
  return 1.f/x;
#endif
}
__device__ __forceinline__ float fast_sig(float x){ return rcp_fast(1.f+__expf(-x)); }
__device__ __forceinline__ float fast_tanh(float x){ float e=__expf(2.f*x); return 1.f-2.f*rcp_fast(e+1.f); }
__device__ __forceinline__ u16 f2bf(float f){
  u32 u = __builtin_bit_cast(u32, f);
  u += 0x7fffu + ((u>>16)&1u);
  return (u16)(u>>16);
}
__device__ __forceinline__ float bf2f(u16 b){
  u32 u = ((u32)b)<<16; return __builtin_bit_cast(float, u);
}
__device__ __forceinline__ u32 cvtpk_bf16(float a, float b){
  u32 p;
  asm("v_cvt_pk_bf16_f32 %0, %1, %2" : "=v"(p) : "v"(a), "v"(b));
  return p;
}
__device__ __forceinline__ u32 packf16(float a, float b){
  half2_t h; h.x = (_Float16)a; h.y = (_Float16)b;
  return __builtin_bit_cast(u32, h);
}
__device__ __forceinline__ float dot2(u32 w, u32 h, float acc){
#if __has_builtin(__builtin_amdgcn_fdot2)
  return __builtin_amdgcn_fdot2(__builtin_bit_cast(half2_t, w),
                                __builtin_bit_cast(half2_t, h), acc, false);
#else
  half2_t a = __builtin_bit_cast(half2_t, w), b = __builtin_bit_cast(half2_t, h);
  return acc + (float)a.x*(float)b.x + (float)a.y*(float)b.y;
#endif
}
__device__ __forceinline__ f32x4 mfma16(short8 a, short8 b, f32x4 c){
  return __builtin_amdgcn_mfma_f32_16x16x32_bf16(a, b, c, 0, 0, 0);
}

// =====================================================================
// K1: convert whh -> f16 thread layouts; weight mats -> bf16 (sawc in
// XOR-swizzled fragment layout); W32 = W3@W2
// =====================================================================
__global__ void __launch_bounds__(256) k_prep1(const float* __restrict__ whh,
    const float* __restrict__ sawl, const float* __restrict__ tawl,
    const float* __restrict__ tawv, const float* __restrict__ sawc,
    const float* __restrict__ w3, const float* __restrict__ w2, char* ws){
  int blk = blockIdx.x, tid = threadIdx.x;
  if (blk < 512){
    // two whh rows per block -> packed f16 pairs at [c][j]
    u32* wq = (u32*)ws;
    for (int rr = 0; rr < 2; ++rr){
      int row = blk*2 + rr;
      float v  = whh[row*256 + tid];
      float vn = __shfl_down(v, 1);
      if ((tid & 1) == 0){
        int typ = row >> 8;      // 0:i 1:f 2:g 3:o
        int j   = row & 255;
        wq[typ*32768 + (tid>>1)*256 + j] = packf16(v, vn);
      }
    }
  } else if (blk < 544){
    int rel = blk - 512;
    int mat = rel >> 3;
    const float* src; u16* dst;
    if (mat==0){ src=sawl; dst=(u16*)(ws+OFF_SAWL); }
    else if (mat==1){ src=tawl; dst=(u16*)(ws+OFF_TAWL); }
    else if (mat==2){ src=tawv; dst=(u16*)(ws+OFF_TAWV); }
    else { src=sawc; dst=(u16*)(ws+OFF_SAWC); }
    int base = (rel & 7)*8192 + tid;
    if (mat < 3){
      for (int i = 0; i < 32; ++i){ int e = base + i*256; dst[e] = f2bf(src[e]); }
    } else {
      // sawc: swizzled store [col][kk ^ ((col&7)<<3)]
      for (int i = 0; i < 32; ++i){
        int e = base + i*256;
        int col = e >> 8, kk = e & 255;
        dst[col*256 + (kk ^ ((col&7)<<3))] = f2bf(src[e]);
      }
    }
  } else {
    int idx = (blk-544)*256 + tid;   // [0,5120)
    int o = idx >> 9, k2 = idx & 511;
    float acc = 0.f;
    for (int m = 0; m < 512; ++m) acc = fmaf(w3[o*512+m], w2[m*512+k2], acc);
    ((float*)(ws+OFF_W32))[idx] = acc;
  }
}

// =====================================================================
// K2: Wc = W32@W1, bc; and per-batch init h0/c0
// =====================================================================
__global__ void __launch_bounds__(256) k_prep2(const float* __restrict__ w1,
    const float* __restrict__ b1, const float* __restrict__ w3,
    const float* __restrict__ b2, const float* __restrict__ b3,
    const float* __restrict__ gaze,
    const float* __restrict__ ihw1, const float* __restrict__ ihb1,
    const float* __restrict__ ihw2, const float* __restrict__ ihb2,
    const float* __restrict__ icw1, const float* __restrict__ icb1,
    const float* __restrict__ icw2, const float* __restrict__ icb2,
    char* ws){
  int blk = blockIdx.x, tid = threadIdx.x;
  const float* W32 = (const float*)(ws+OFF_W32);
  if (blk < 20){
    int idx = blk*256 + tid; int o = idx>>9, k = idx&511;
    float acc = 0.f;
    for (int m = 0; m < 512; ++m) acc = fmaf(W32[o*512+m], w1[m*512+k], acc);
    ((float*)(ws+OFF_WC))[idx] = acc;
  } else if (blk == 20){
    if (tid < 10){
      float acc = b3[tid];
      for (int m = 0; m < 512; ++m) acc = fmaf(W32[tid*512+m], b1[m], acc);
      for (int m = 0; m < 512; ++m) acc = fmaf(w3[tid*512+m], b2[m], acc);
      ((float*)(ws+OFF_BC))[tid] = acc;
    }
  } else {
    int b = blk - 21;
    __shared__ float red0[128], red1[128], red2[128];
    __shared__ float mg[3];
    __shared__ float x1[256];
    if (tid < 128){
      const float* gp = gaze + b*384 + tid*3;
      red0[tid] = gp[0]; red1[tid] = gp[1]; red2[tid] = gp[2];
    }
    __syncthreads();
    for (int s = 64; s >= 1; s >>= 1){
      if (tid < s){ red0[tid]+=red0[tid+s]; red1[tid]+=red1[tid+s]; red2[tid]+=red2[tid+s]; }
      __syncthreads();
    }
    if (tid == 0){ mg[0]=red0[0]*(1.f/128.f); mg[1]=red1[0]*(1.f/128.f); mg[2]=red2[0]*(1.f/128.f); }
    __syncthreads();
    for (int which = 0; which < 2; ++which){
      const float* aw1 = which? icw1 : ihw1; const float* ab1 = which? icb1 : ihb1;
      const float* aw2 = which? icw2 : ihw2; const float* ab2 = which? icb2 : ihb2;
      float v = fast_tanh(fmaf(aw1[tid*3+2],mg[2], fmaf(aw1[tid*3+1],mg[1], fmaf(aw1[tid*3],mg[0], ab1[tid]))));
      x1[tid] = v;
      __syncthreads();
      float acc = ab2[tid];
      for (int k = 0; k < 256; ++k) acc = fmaf(aw2[tid*256+k], x1[k], acc);
      float h0 = fast_tanh(fast_tanh(acc));
      if (which == 0){
        float* hseq = (float*)(ws+OFF_HSEQ);
        hseq[(size_t)(0*64 + b)*256 + tid] = h0;
        float hn = __shfl_down(h0, 1);
        if ((tid&1)==0){
          ((u32*)(ws+OFF_HSEQB))[((size_t)(0*64+b)*256 + tid)>>1] = ((u32)f2bf(hn)<<16) | f2bf(h0);
          ((u32*)(ws+OFF_H0F16))[b*128 + (tid>>1)] = packf16(h0, hn);
        }
      } else {
        ((float*)(ws+OFF_C0))[b*256 + tid] = h0;
      }
      __syncthreads();
    }
  }
}

// =====================================================================
// K3: LSTM sequential pass (proven round-5 v2 structure, 212 us).
// =====================================================================
__global__ void __launch_bounds__(512, 2) k_lstm(const float* __restrict__ gaze,
    const float* __restrict__ wih, const float* __restrict__ bih,
    const float* __restrict__ bhh, char* ws){
  int b = blockIdx.x, tid = threadIdx.x;
  int half = tid >> 8;            // 0: i/g rows, 1: f/o rows
  int j = tid & 255;
  __shared__ u32 lds_w[16*2048];            // 128KB: rowB pairs c=64..127
  __shared__ __align__(16) u32 hbuf[2][128];
  __shared__ float p_lds[256];
  __shared__ float g_lds[384];

  const u32* wq = (const u32*)ws;
  const u32* wA = wq + (half ? 1 : 0) * 32768;   // i or f
  const u32* wB = wq + (half ? 3 : 2) * 32768;   // g or o
  u32 w0[128], w1r[64];
#pragma unroll
  for (int c = 0; c < 128; ++c) w0[c] = wA[c*256 + j];
#pragma unroll
  for (int c = 0; c < 64; ++c)  w1r[c] = wB[c*256 + j];
#pragma unroll
  for (int cq = 0; cq < 16; ++cq)
#pragma unroll
    for (int q = 0; q < 4; ++q)
      lds_w[cq*2048 + tid*4 + q] = wB[(64 + cq*4 + q)*256 + j];

  if (tid < 384) g_lds[tid] = gaze[b*384 + tid];
  if (tid < 128) hbuf[0][tid] = ((const u32*)(ws+OFF_H0F16))[b*128 + tid];
  float creg = half ? ((const float*)(ws+OFF_C0))[b*256 + j] : 0.f;

  int rA = half ? 256 + j : j;
  int rB = half ? 768 + j : 512 + j;
  float baseA = bih[rA] + bhh[rA];
  float baseB = bih[rB] + bhh[rB];
  float uA0 = wih[rA*3], uA1 = wih[rA*3+1], uA2 = wih[rA*3+2];
  float uB0 = wih[rB*3], uB1 = wih[rB*3+1], uB2 = wih[rB*3+2];

  float* hseq = (float*)(ws+OFF_HSEQ);
  u32* hseqb = (u32*)(ws+OFF_HSEQB);
  float hv_prev = 0.f; u32 hpk_prev = 0;
  __syncthreads();

  for (int t = 0; t < 128; ++t){
    int cur = t & 1, nxt = cur ^ 1;
    // delayed global store of h_t (retires during this step's dot phase)
    if (half == 1 && t > 0){
      hseq[((size_t)t*64 + b)*256 + j] = hv_prev;
      if ((j & 1) == 0)
        hseqb[(((size_t)t*64 + b)*256 + j)>>1] = hpk_prev;
    }
    float g0 = g_lds[t*3], g1 = g_lds[t*3+1], g2 = g_lds[t*3+2];
    float aA0 = fmaf(uA2,g2, fmaf(uA1,g1, fmaf(uA0,g0, baseA))), aA1 = 0.f;
    float aB0 = fmaf(uB2,g2, fmaf(uB1,g1, fmaf(uB0,g0, baseB))), aB1 = 0.f;
#pragma unroll
    for (int c4 = 0; c4 < 32; ++c4){
      uint4 h4 = *reinterpret_cast<const uint4*>(&hbuf[cur][c4*4]);
      u32 wb0, wb1, wb2, wb3;
      if (c4 < 16){
        wb0 = w1r[c4*4]; wb1 = w1r[c4*4+1]; wb2 = w1r[c4*4+2]; wb3 = w1r[c4*4+3];
      } else {
        uint4 wv = *reinterpret_cast<const uint4*>(&lds_w[(c4-16)*2048 + tid*4]);
        wb0 = wv.x; wb1 = wv.y; wb2 = wv.z; wb3 = wv.w;
      }
      aA0 = dot2(w0[c4*4+0], h4.x, aA0); aB0 = dot2(wb0, h4.x, aB0);
      aA1 = dot2(w0[c4*4+1], h4.y, aA1); aB1 = dot2(wb1, h4.y, aB1);
      aA0 = dot2(w0[c4*4+2], h4.z, aA0); aB0 = dot2(wb2, h4.z, aB0);
      aA1 = dot2(w0[c4*4+3], h4.w, aA1); aB1 = dot2(wb3, h4.w, aB1);
    }
    float aA = aA0 + aA1, aB = aB0 + aB1;
    if (half == 0){
      p_lds[j] = fast_sig(aA) * fast_tanh(aB);   // sig(i)*tanh(g)
    }
    __syncthreads();
    if (half == 1){
      float p = p_lds[j];
      creg = fmaf(fast_sig(aA), creg, p);        // sig(f)*c + p
      float hv = fast_sig(aB) * fast_tanh(creg); // sig(o)*tanh(c)
      float hn = __shfl_down(hv, 1);
      if ((j & 1) == 0) hbuf[nxt][j>>1] = packf16(hv, hn);
      hv_prev = hv;
      hpk_prev = ((u32)f2bf(hn)<<16) | f2bf(hv);
    }
    __syncthreads();
  }
  // tail: store h_128
  if (half == 1){
    hseq[((size_t)128*64 + b)*256 + j] = hv_prev;
    if ((j & 1) == 0)
      hseqb[(((size_t)128*64 + b)*256 + j)>>1] = hpk_prev;
  }
}

// =====================================================================
// K4: Hp_sa = a@sa_wl^T + (sa_bl+sa_bc);  Hq = a@ta_wl^T + (ta_bl+ta_bv)
// =====================================================================
__global__ void __launch_bounds__(256) k_proj1(const float* __restrict__ sabl,
    const float* __restrict__ sabc, const float* __restrict__ tabl,
    const float* __restrict__ tabv, char* ws){
  int bx = blockIdx.x, which = blockIdx.y;
  const u16* A = (const u16*)(ws+OFF_HSEQB);
  const u16* B = (const u16*)(ws + (which? OFF_TAWL : OFF_SAWL));
  float* Out   = (float*)(ws + (which? OFF_HQ : OFF_HPSA));
  const float* bp1 = which? tabl : sabl;
  const float* bp2 = which? tabv : sabc;
  int tid = threadIdx.x, w = tid>>6, l = tid&63;
  int lr = l&15, lk = l>>4;
  int rb = bx*64;
  short8 afr[4][8];
#pragma unroll
  for (int m = 0; m < 4; ++m)
#pragma unroll
    for (int k = 0; k < 8; ++k)
      afr[m][k] = *(const short8*)(const void*)(A + (size_t)(rb + m*16 + lr)*256 + k*32 + lk*8);
#pragma unroll
  for (int n = 0; n < 4; ++n){
    int cb = w*64 + n*16;
    int col = cb + lr;
    float bias = bp1[col] + bp2[col];
    f32x4 a0 = {0.f,0.f,0.f,0.f}, a1 = a0, a2 = a0, a3 = a0;
#pragma unroll
    for (int k = 0; k < 8; ++k){
      short8 bf = *(const short8*)(const void*)(B + (size_t)col*256 + k*32 + lk*8);
      a0 = mfma16(afr[0][k], bf, a0);
      a1 = mfma16(afr[1][k], bf, a1);
      a2 = mfma16(afr[2][k], bf, a2);
      a3 = mfma16(afr[3][k], bf, a3);
    }
#pragma unroll
    for (int q = 0; q < 4; ++q){
      Out[(size_t)(rb + 0*16 + lk*4 + q)*256 + col] = a0[q] + bias;
      Out[(size_t)(rb + 1*16 + lk*4 + q)*256 + col] = a1[q] + bias;
      Out[(size_t)(rb + 2*16 + lk*4 + q)*256 + col] = a2[q] + bias;
      Out[(size_t)(rb + 3*16 + lk*4 + q)*256 + col] = a3[q] + bias;
    }
  }
}

// =====================================================================
// K5 v5b: spatial attention, 512 threads, grid 512 (SP_ROWS=16), TWO
// blocks per CU. __launch_bounds__(512,2): 128-VGPR budget -> the ~100
// reg working set (breg 32 + pf 20 + afr/zacc) fits with NO spill;
// 128 VGPR x 16 waves = full pool -> 2 blocks/CU resident (round-8's
// 46% occupancy) without round-8's 240MB scratch traffic.
// =====================================================================
__global__ void __launch_bounds__(512, 2) k_spatial(const float* __restrict__ feat,
    const float* __restrict__ sawz, char* ws){
  __shared__ __align__(16) u16 featb[48*256];   // rows 36-47 garbage (masked)
  __shared__ __align__(16) float hp[256];
  __shared__ float wzs[256];
  __shared__ float zsbuf[8][48];
  __shared__ float swl[36];
  __shared__ float psum[2][256];
  int bx = blockIdx.x, tid = threadIdx.x, w = tid>>6, l = tid&63;
  int lr = l&15, lk = l>>4;
  int colbase = w*32;
  const float* hpsa = (const float*)(ws+OFF_HPSA);
  const u16* Bw = (const u16*)(ws+OFF_SAWC);

  // B fragments -> registers (once per block)
  short8 breg[2][8];
#pragma unroll
  for (int n = 0; n < 2; ++n){
    int col = colbase + n*16 + lr;
#pragma unroll
    for (int k = 0; k < 8; ++k)
      breg[n][k] = *(const short8*)(const void*)(Bw + (size_t)col*256 + ((k*32 + lk*8) ^ ((col&7)<<3)));
  }
  if (tid < 256) wzs[tid] = sawz[tid];

  // prefetch row 0
  float4 pf[5]; float4 ph;
  {
    int r0 = bx*SP_ROWS;
    int t = r0>>6, b = r0&63;
    const float4* fb = (const float4*)(feat + ((size_t)(b*128 + t))*9216);
#pragma unroll
    for (int ii = 0; ii < 4; ++ii) pf[ii] = fb[tid + ii*512];
    if (tid < 256) pf[4] = fb[2048 + tid];
    if (tid < 64) ph = ((const float4*)(hpsa + (size_t)r0*256))[tid];
  }
  __syncthreads();

  for (int i = 0; i < SP_ROWS; ++i){
    int r = bx*SP_ROWS + i;
    // ---- stage current row's feat (bf16, swizzled) + hp ----
#pragma unroll
    for (int ii = 0; ii < 4; ++ii){
      int e = tid + ii*512;
      int g = e >> 6, c4 = e & 63;
      uint2 pp;
      pp.x = cvtpk_bf16(pf[ii].x, pf[ii].y);
      pp.y = cvtpk_bf16(pf[ii].z, pf[ii].w);
      *reinterpret_cast<uint2*>((u32*)featb + g*128 + ((c4*2) ^ ((g&7)<<2))) = pp;
    }
    if (tid < 256){
      int e = 2048 + tid;
      int g = e >> 6, c4 = e & 63;
      uint2 pp;
      pp.x = cvtpk_bf16(pf[4].x, pf[4].y);
      pp.y = cvtpk_bf16(pf[4].z, pf[4].w);
      *reinterpret_cast<uint2*>((u32*)featb + g*128 + ((c4*2) ^ ((g&7)<<2))) = pp;
    }
    if (tid < 64) *reinterpret_cast<float4*>(hp + tid*4) = ph;
    __syncthreads();
    // ---- prefetch next row ----
    if (i + 1 < SP_ROWS){
      int rn = r + 1;
      int t = rn>>6, b = rn&63;
      const float4* fb = (const float4*)(feat + ((size_t)(b*128 + t))*9216);
#pragma unroll
      for (int ii = 0; ii < 4; ++ii) pf[ii] = fb[tid + ii*512];
      if (tid < 256) pf[4] = fb[2048 + tid];
      if (tid < 64) ph = ((const float4*)(hpsa + (size_t)rn*256))[tid];
    }
    // ---- MFMA: per m load afr, 2 n-groups from registers ----
    float zacc[3][4] = {{0.f}};
#pragma unroll
    for (int m = 0; m < 3; ++m){
      short8 afr[8];
#pragma unroll
      for (int k = 0; k < 8; ++k){
        int g = m*16 + lr;
        afr[k] = *(const short8*)(const void*)(featb + g*256 + ((k*32 + lk*8) ^ ((g&7)<<3)));
      }
#pragma unroll
      for (int n = 0; n < 2; ++n){
        f32x4 a = {0.f,0.f,0.f,0.f};
#pragma unroll
        for (int k = 0; k < 8; ++k) a = mfma16(afr[k], breg[n][k], a);
        int col = colbase + n*16 + lr;
        float hpl = hp[col], wzv = wzs[col];
#pragma unroll
        for (int q = 0; q < 4; ++q)
          zacc[m][q] += fast_tanh(a[q] + hpl)*wzv;
      }
    }
#pragma unroll
    for (int m = 0; m < 3; ++m)
#pragma unroll
      for (int q = 0; q < 4; ++q){
        float v = zacc[m][q];
        v += __shfl_xor(v, 1); v += __shfl_xor(v, 2);
        v += __shfl_xor(v, 4); v += __shfl_xor(v, 8);
        if (lr == 0) zsbuf[w][m*16 + lk*4 + q] = v;
      }
    __syncthreads();
    // ---- softmax over g (wave 0) ----
    if (w == 0){
      float z = -1e30f;
      if (l < 36)
        z = zsbuf[0][l]+zsbuf[1][l]+zsbuf[2][l]+zsbuf[3][l]
          + zsbuf[4][l]+zsbuf[5][l]+zsbuf[6][l]+zsbuf[7][l];
      float mx = z;
      for (int d = 1; d < 64; d <<= 1) mx = fmaxf(mx, __shfl_xor(mx, d));
      float e = (l < 36)? __expf(z - mx) : 0.f;
      float s = e;
      for (int d = 1; d < 64; d <<= 1) s += __shfl_xor(s, d);
      if (l < 36) swl[l] = e * rcp_fast(s);
    }
    __syncthreads();
    // ---- weighted sum: split g 0-17 / 18-35 across thread halves ----
    {
      int hsel = tid >> 8, col = tid & 255;
      float part = 0.f;
#pragma unroll
      for (int gg = 0; gg < 18; ++gg){
        int g = hsel*18 + gg;
        part = fmaf(swl[g], bf2f(featb[g*256 + (col ^ ((g&7)<<3))]), part);
      }
      psum[hsel][col] = part;
    }
    __syncthreads();
    if (tid < 256){
      float acc = psum[0][tid] + psum[1][tid];
      ((float*)(ws+OFF_SPAT))[(size_t)r*256 + tid] = acc;
      float an = __shfl_down(acc, 1);
      if ((tid & 1) == 0)
        ((u32*)(ws+OFF_SPATB))[((size_t)r*256 + tid)>>1] = cvtpk_bf16(acc, an);
    }
  }
}

// =====================================================================
// K6: zscore[r] = rowsum( tanh(spat@ta_wv^T + Hq) * ta_wz )
// =====================================================================
__global__ void __launch_bounds__(256) k_proj2(const float* __restrict__ tawz, char* ws){
  int bx = blockIdx.x;
  int tid = threadIdx.x, w = tid>>6, l = tid&63;
  int lr = l&15, lk = l>>4;
  int rb = bx*64;
  const u16* A = (const u16*)(ws+OFF_SPATB);
  const u16* B = (const u16*)(ws+OFF_TAWV);
  const float* Hq = (const float*)(ws+OFF_HQ);
  __shared__ float zbuf[4][64];
  short8 afr[4][8];
#pragma unroll
  for (int m = 0; m < 4; ++m)
#pragma unroll
    for (int k = 0; k < 8; ++k)
      afr[m][k] = *(const short8*)(const void*)(A + (size_t)(rb + m*16 + lr)*256 + k*32 + lk*8);
  float racc[4][4] = {{0.f}};
#pragma unroll
  for (int n = 0; n < 4; ++n){
    int col = w*64 + n*16 + lr;
    float tzl = tawz[col];
    f32x4 a0 = {0.f,0.f,0.f,0.f}, a1 = a0, a2 = a0, a3 = a0;
#pragma unroll
    for (int k = 0; k < 8; ++k){
      short8 bf = *(const short8*)(const void*)(B + (size_t)col*256 + k*32 + lk*8);
      a0 = mfma16(afr[0][k], bf, a0);
      a1 = mfma16(afr[1][k], bf, a1);
      a2 = mfma16(afr[2][k], bf, a2);
      a3 = mfma16(afr[3][k], bf, a3);
    }
#pragma unroll
    for (int q = 0; q < 4; ++q){
      racc[0][q] += fast_tanh(a0[q] + Hq[(size_t)(rb + 0*16 + lk*4 + q)*256 + col]) * tzl;
      racc[1][q] += fast_tanh(a1[q] + Hq[(size_t)(rb + 1*16 + lk*4 + q)*256 + col]) * tzl;
      racc[2][q] += fast_tanh(a2[q] + Hq[(size_t)(rb + 2*16 + lk*4 + q)*256 + col]) * tzl;
      racc[3][q] += fast_tanh(a3[q] + Hq[(size_t)(rb + 3*16 + lk*4 + q)*256 + col]) * tzl;
    }
  }
#pragma unroll
  for (int m = 0; m < 4; ++m)
#pragma unroll
    for (int q = 0; q < 4; ++q){
      float v = racc[m][q];
      v += __shfl_xor(v, 1); v += __shfl_xor(v, 2);
      v += __shfl_xor(v, 4); v += __shfl_xor(v, 8);
      if (lr == 0) zbuf[w][m*16 + lk*4 + q] = v;
    }
  __syncthreads();
  if (tid < 64)
    ((float*)(ws+OFF_ZSC))[rb + tid] = zbuf[0][tid]+zbuf[1][tid]+zbuf[2][tid]+zbuf[3][tid];
}

// =====================================================================
// K7: windowed temporal softmax + temp + collapsed classifier
// =====================================================================
__global__ void __launch_bounds__(256) k_final(float* __restrict__ out, char* ws){
  int bx = blockIdx.x;
  int b = bx & 63, tb = bx >> 6;
  int t0 = tb*8;
  int tid = threadIdx.x;
  int wv = tid>>6, l = tid&63;
  __shared__ float spw[23][256];
  __shared__ float zw[23];
  __shared__ float WcL[5120];
  __shared__ float bcL[10];
  __shared__ float w16[16];
  __shared__ float wpart[4][10];
  const float* spat = (const float*)(ws+OFF_SPAT);
  const float* zsc  = (const float*)(ws+OFF_ZSC);
  const float* hseq = (const float*)(ws+OFF_HSEQ);
  const float* Wc   = (const float*)(ws+OFF_WC);
#pragma unroll
  for (int i = 0; i < 20; ++i) WcL[tid + i*256] = Wc[tid + i*256];
  if (tid < 10) bcL[tid] = ((const float*)(ws+OFF_BC))[tid];
  for (int i = 0; i < 23; ++i){
    int tau = t0 - 15 + i;
    spw[i][tid] = (tau >= 0)? spat[(size_t)(tau*64 + b)*256 + tid] : 0.f;
  }
  if (tid < 23){
    int tau = t0 - 15 + tid;
    zw[tid] = (tau >= 0)? zsc[tau*64 + b] : -1e9f;
  }
  __syncthreads();
  for (int dt = 0; dt < 8; ++dt){
    int t = t0 + dt;
    if (wv == 0 && l < 16){
      float z = zw[dt + l];
      float mx = z;
      mx = fmaxf(mx, __shfl_xor(mx,1)); mx = fmaxf(mx, __shfl_xor(mx,2));
      mx = fmaxf(mx, __shfl_xor(mx,4)); mx = fmaxf(mx, __shfl_xor(mx,8));
      float e = __expf(z - mx);
      float s = e;
      s += __shfl_xor(s,1); s += __shfl_xor(s,2); s += __shfl_xor(s,4); s += __shfl_xor(s,8);
      w16[l] = e / s;
    }
    __syncthreads();
    float temp = 0.f;
#pragma unroll
    for (int qi = 0; qi < 16; ++qi) temp = fmaf(w16[qi], spw[dt+qi][tid], temp);
    float hc = hseq[(size_t)((t+1)*64 + b)*256 + tid];
    float po[10];
#pragma unroll
    for (int o = 0; o < 10; ++o){
      float v = fmaf(temp, WcL[o*512 + tid], hc*WcL[o*512 + 256 + tid]);
      v += __shfl_xor(v,1);  v += __shfl_xor(v,2);  v += __shfl_xor(v,4);
      v += __shfl_xor(v,8);  v += __shfl_xor(v,16); v += __shfl_xor(v,32);
      po[o] = v;
    }
    if (l == 0){
#pragma unroll
      for (int o = 0; o < 10; ++o) wpart[wv][o] = po[o];
    }
    __syncthreads();
    if (tid < 10)
      out[(size_t)(t*64 + b)*10 + tid] = wpart[0][tid]+wpart[1][tid]+wpart[2][tid]+wpart[3][tid] + bcL[tid];
    __syncthreads();
  }
}

// =====================================================================
extern "C" void kernel_launch(void* const* d_in, const int* in_sizes, int n_in,
                              void* d_out, int out_size, void* d_ws, size_t ws_size,
                              hipStream_t stream){
  const float* feat = (const float*)d_in[0];
  const float* gaze = (const float*)d_in[1];
  const float* ihw1 = (const float*)d_in[2];  const float* ihb1 = (const float*)d_in[3];
  const float* ihw2 = (const float*)d_in[4];  const float* ihb2 = (const float*)d_in[5];
  const float* icw1 = (const float*)d_in[6];  const float* icb1 = (const float*)d_in[7];
  const float* icw2 = (const float*)d_in[8];  const float* icb2 = (const float*)d_in[9];
  const float* wih  = (const float*)d_in[10]; const float* whh  = (const float*)d_in[11];
  const float* bih  = (const float*)d_in[12]; const float* bhh  = (const float*)d_in[13];
  const float* sawl = (const float*)d_in[14]; const float* sabl = (const float*)d_in[15];
  const float* sawc = (const float*)d_in[16]; const float* sabc = (const float*)d_in[17];
  const float* sawz = (const float*)d_in[18];
  const float* tawl = (const float*)d_in[19]; const float* tabl = (const float*)d_in[20];
  const float* tawv = (const float*)d_in[21]; const float* tabv = (const float*)d_in[22];
  const float* tawz = (const float*)d_in[23];
  const float* w1 = (const float*)d_in[24]; const float* b1 = (const float*)d_in[25];
  const float* w2 = (const float*)d_in[26]; const float* b2 = (const float*)d_in[27];
  const float* w3 = (const float*)d_in[28]; const float* b3 = (const float*)d_in[29];
  char* ws = (char*)d_ws;
  float* out = (float*)d_out;
  if (ws_size < (size_t)WS_NEEDED) return;

  k_prep1<<<dim3(564), dim3(256), 0, stream>>>(whh, sawl, tawl, tawv, sawc, w3, w2, ws);
  k_prep2<<<dim3(85), dim3(256), 0, stream>>>(w1, b1, w3, b2, b3, gaze,
      ihw1, ihb1, ihw2, ihb2, icw1, icb1, icw2, icb2, ws);
  k_lstm<<<dim3(64), dim3(512), 0, stream>>>(gaze, wih, bih, bhh, ws);
  k_proj1<<<dim3(128, 2), dim3(256), 0, stream>>>(sabl, sabc, tabl, tabv, ws);
  k_spatial<<<dim3(512), dim3(512), 0, stream>>>(feat, sawz, ws);
  k_proj2<<<dim3(128), dim3(256), 0, stream>>>(tawz, ws);
  k_final<<<dim3(1024), dim3(256), 0, stream>>>(out, ws);
}